// Round 2
// baseline (368.910 us; speedup 1.0000x reference)
//
#include <hip/hip_runtime.h>

// BayesianLayer: out[b,o] = sum_i x[b,i]*(eps[b,i,o]*softplus(ro[i,o]) + mu[i,o])
//                          + eps_bias[b,o]*softplus(ro_bias[o]) + mu_bias[o]
// B=64, IN=1024, OUT=1024, fp32. Memory-bound on eps (256 MB, read-once).
//
// Deterministic 3-kernel pipeline (NO atomics, NO output memset — the R1
// memset+atomicAdd combo lost one chunk partial under graph replay):
//   A: sig[i,o]   = softplus(ro[i,o])              -> ws[0 .. 1M)
//   B: part[b,c,o]= sum_{i in chunk c} x*(eps*sig+mu) -> ws[1M .. 3M)
//   C: out[b,o]   = sum_c part + eps_bias*softplus(ro_bias) + mu_bias

#define BB   64
#define INN  1024
#define OUTT 1024
#define B_T  4               // batch rows per main block
#define ICH  32              // split-K chunks over IN
#define I_C  (INN / ICH)     // 32 i's per main block

typedef float f4 __attribute__((ext_vector_type(4)));

__device__ __forceinline__ float softplus_f(float v) {
    return fmaxf(v, 0.0f) + log1pf(__expf(-fabsf(v)));
}

// ---- kernel A: sig = softplus(ro), 1M elements as 256K float4 ----
__global__ __launch_bounds__(256) void bayes_sig(
    const float* __restrict__ ro, float* __restrict__ sig)
{
    const int g = blockIdx.x * 256 + threadIdx.x;      // float4 index
    const f4 r = *(const f4*)(ro + (size_t)g * 4);
    f4 s;
    s.x = softplus_f(r.x); s.y = softplus_f(r.y);
    s.z = softplus_f(r.z); s.w = softplus_f(r.w);
    *(f4*)(sig + (size_t)g * 4) = s;
}

// ---- kernel B: split-K partials ----
__global__ __launch_bounds__(256) void bayes_main(
    const float* __restrict__ x,        // [B, IN]
    const float* __restrict__ mu,       // [IN, OUT]
    const float* __restrict__ sig,      // [IN, OUT] (precomputed softplus)
    const float* __restrict__ eps,      // [B, IN, OUT]
    float* __restrict__ part)           // [B, ICH, OUT]
{
    __shared__ float xs[B_T][I_C];

    const int t  = threadIdx.x;
    const int o  = t << 2;
    const int c  = blockIdx.x;          // chunk
    const int b0 = blockIdx.y * B_T;
    const int i0 = c * I_C;

    if (t < B_T * I_C) {
        const int b  = t / I_C;
        const int il = t % I_C;
        xs[b][il] = x[(b0 + b) * INN + i0 + il];
    }
    __syncthreads();

    f4 acc[B_T];
#pragma unroll
    for (int b = 0; b < B_T; ++b) acc[b] = (f4)0.0f;

#pragma unroll 4
    for (int il = 0; il < I_C; ++il) {
        const int i = i0 + il;
        const f4 sg4 = *(const f4*)(sig + (size_t)i * OUTT + o);
        const f4 mu4 = *(const f4*)(mu  + (size_t)i * OUTT + o);
#pragma unroll
        for (int b = 0; b < B_T; ++b) {
            const float xb = xs[b][il];
            const f4 e = __builtin_nontemporal_load(
                (const f4*)(eps + ((size_t)(b0 + b) * INN + i) * OUTT + o));
            acc[b].x = fmaf(xb, fmaf(e.x, sg4.x, mu4.x), acc[b].x);
            acc[b].y = fmaf(xb, fmaf(e.y, sg4.y, mu4.y), acc[b].y);
            acc[b].z = fmaf(xb, fmaf(e.z, sg4.z, mu4.z), acc[b].z);
            acc[b].w = fmaf(xb, fmaf(e.w, sg4.w, mu4.w), acc[b].w);
        }
    }

#pragma unroll
    for (int b = 0; b < B_T; ++b) {
        *(f4*)(part + ((size_t)(b0 + b) * ICH + c) * OUTT + o) = acc[b];
    }
}

// ---- kernel C: reduce 32 partials + bias ----
__global__ __launch_bounds__(256) void bayes_reduce(
    const float* __restrict__ part,     // [B, ICH, OUT]
    const float* __restrict__ mu_bias,  // [OUT]
    const float* __restrict__ ro_bias,  // [OUT]
    const float* __restrict__ eps_bias, // [B, OUT]
    float* __restrict__ out)            // [B, OUT]
{
    const int g  = blockIdx.x * 256 + threadIdx.x;   // float4 index over [B*OUT/4]
    const int b  = g >> 8;                           // 256 float4 per row
    const int o  = (g & 255) << 2;

    f4 s = (f4)0.0f;
#pragma unroll
    for (int c = 0; c < ICH; ++c) {
        const f4 p = *(const f4*)(part + ((size_t)b * ICH + c) * OUTT + o);
        s.x += p.x; s.y += p.y; s.z += p.z; s.w += p.w;
    }

    const f4 rb = *(const f4*)(ro_bias + o);
    const f4 mb = *(const f4*)(mu_bias + o);
    const f4 eb = *(const f4*)(eps_bias + (size_t)b * OUTT + o);
    s.x += fmaf(eb.x, softplus_f(rb.x), mb.x);
    s.y += fmaf(eb.y, softplus_f(rb.y), mb.y);
    s.z += fmaf(eb.z, softplus_f(rb.z), mb.z);
    s.w += fmaf(eb.w, softplus_f(rb.w), mb.w);

    *(f4*)(out + (size_t)g * 4) = s;
}

// ---- fallback (ws too small): single deterministic kernel, no scratch ----
__global__ __launch_bounds__(256) void bayes_mono(
    const float* __restrict__ x, const float* __restrict__ mu,
    const float* __restrict__ ro, const float* __restrict__ mu_bias,
    const float* __restrict__ ro_bias, const float* __restrict__ eps,
    const float* __restrict__ eps_bias, float* __restrict__ out)
{
    const int t = threadIdx.x;
    const int o = t << 2;
    const int b = blockIdx.x;

    f4 acc = (f4)0.0f;
    for (int i = 0; i < INN; ++i) {
        const float xb = x[b * INN + i];
        const f4 r4 = *(const f4*)(ro + (size_t)i * OUTT + o);
        const f4 m4 = *(const f4*)(mu + (size_t)i * OUTT + o);
        const f4 e  = *(const f4*)(eps + ((size_t)b * INN + i) * OUTT + o);
        acc.x = fmaf(xb, fmaf(e.x, softplus_f(r4.x), m4.x), acc.x);
        acc.y = fmaf(xb, fmaf(e.y, softplus_f(r4.y), m4.y), acc.y);
        acc.z = fmaf(xb, fmaf(e.z, softplus_f(r4.z), m4.z), acc.z);
        acc.w = fmaf(xb, fmaf(e.w, softplus_f(r4.w), m4.w), acc.w);
    }
    const f4 rb = *(const f4*)(ro_bias + o);
    const f4 mb = *(const f4*)(mu_bias + o);
    const f4 eb = *(const f4*)(eps_bias + (size_t)b * OUTT + o);
    acc.x += fmaf(eb.x, softplus_f(rb.x), mb.x);
    acc.y += fmaf(eb.y, softplus_f(rb.y), mb.y);
    acc.z += fmaf(eb.z, softplus_f(rb.z), mb.z);
    acc.w += fmaf(eb.w, softplus_f(rb.w), mb.w);
    *(f4*)(out + (size_t)b * OUTT + o) = acc;
}

extern "C" void kernel_launch(void* const* d_in, const int* in_sizes, int n_in,
                              void* d_out, int out_size, void* d_ws, size_t ws_size,
                              hipStream_t stream) {
    const float* x        = (const float*)d_in[0];
    const float* mu       = (const float*)d_in[1];
    const float* ro       = (const float*)d_in[2];
    const float* mu_bias  = (const float*)d_in[3];
    const float* ro_bias  = (const float*)d_in[4];
    const float* eps      = (const float*)d_in[5];
    const float* eps_bias = (const float*)d_in[6];
    float* out = (float*)d_out;

    const size_t sig_elems  = (size_t)INN * OUTT;        // 1M floats
    const size_t part_elems = (size_t)BB * ICH * OUTT;   // 2M floats
    const size_t need = (sig_elems + part_elems) * sizeof(float);  // 12 MB

    if (ws_size >= need) {
        float* sig  = (float*)d_ws;
        float* part = sig + sig_elems;

        bayes_sig<<<sig_elems / 1024, 256, 0, stream>>>(ro, sig);
        dim3 grid(ICH, BB / B_T);   // 32 x 16 = 512 blocks, 2 blocks/CU
        bayes_main<<<grid, 256, 0, stream>>>(x, mu, sig, eps, part);
        bayes_reduce<<<(BB * OUTT / 4) / 256, 256, 0, stream>>>(
            part, mu_bias, ro_bias, eps_bias, out);
    } else {
        bayes_mono<<<BB, 256, 0, stream>>>(x, mu, ro, mu_bias, ro_bias,
                                           eps, eps_bias, out);
    }
}